// Round 6
// baseline (140.689 us; speedup 1.0000x reference)
//
#include <hip/hip_runtime.h>
#include <hip/hip_bf16.h>

// Ensemble Q-network, fused, transposed ([features x batch]).
//   h1^T = relu(W1^T x^T + b1);  acc = W2^T h1^T + b2;  out = W3 . relu(acc)  in-register.
// R6: BT=64 batch tile -> h1 LDS 32 KB -> 3 blocks/CU (launch_bounds(512,6), 24
// waves/CU, +50% TLP vs R5). Layer 1: mfma 16x16x32; layer 2: mfma 32x32x16 with
// depth-1 register prefetch of A (L2) and B (LDS); kt=0 A-frags + b2 issued before
// the epilogue-1 barrier. h1 frag-chunk layout [ch/8][col][8]. 2 dispatches total.

typedef __attribute__((ext_vector_type(8))) short bf16x8;    // 8 bf16 (4 VGPRs)
typedef __attribute__((ext_vector_type(4))) float f32x4;     // 16x16 MFMA C/D
typedef __attribute__((ext_vector_type(16))) float f32x16;   // 32x32 MFMA C/D

#define B_TOTAL 32768
#define NQ 10
#define HDIM 256
#define BT 64               // batch cols per block

#define XP_ELEMS  (B_TOTAL * 32)            // bf16 x, k-padded to 32
#define W1P_ELEMS (NQ * 16 * 64 * 8)        // [n][mtile16][lane64][j8]   (16x16 A-frags)
#define W2P_ELEMS (NQ * 16 * 8 * 64 * 8)    // [n][kt16][mtile8][lane64][j8] (32x32 A-frags)

__device__ __forceinline__ unsigned short f2bf(float f) {
  unsigned int u = __float_as_uint(f);
  u = u + 0x7FFFu + ((u >> 16) & 1u);
  return (unsigned short)(u >> 16);
}

__device__ __forceinline__ unsigned int pk2bf(float a, float b) {
  union { __hip_bfloat162 h; unsigned int u; } cv;
  cv.h = __float22bfloat162_rn(make_float2(a, b));
  return cv.u;
}

// ---- single pack dispatch: x, W1^T (16x16 A-order), W2^T (32x32 A-order) ----
__global__ void pack_all_kernel(const float* __restrict__ state,
                                const float* __restrict__ action,
                                const float* __restrict__ W1,
                                const float* __restrict__ W2,
                                unsigned short* __restrict__ xp,
                                unsigned short* __restrict__ w1p,
                                unsigned short* __restrict__ w2p) {
  int t = blockIdx.x * 256 + threadIdx.x;   // 872 * 256 = 223232 exactly
  const int NX  = B_TOTAL * 4;              // 131072 uint4 chunks of xp
  const int NW1 = NQ * 16 * 64;             // 10240
  if (t < NX) {
    int b = t >> 2, seg = t & 3;
    unsigned short v[8];
    if (seg < 2) {
      const float* sp = state + (size_t)b * 17 + seg * 8;
#pragma unroll
      for (int j = 0; j < 8; j++) v[j] = f2bf(sp[j]);
    } else if (seg == 2) {
      v[0] = f2bf(state[(size_t)b * 17 + 16]);
#pragma unroll
      for (int j = 0; j < 6; j++) v[1 + j] = f2bf(action[(size_t)b * 6 + j]);
      v[7] = 0;
    } else {
#pragma unroll
      for (int j = 0; j < 8; j++) v[j] = 0;
    }
    *(uint4*)&xp[(size_t)t * 8] = *(const uint4*)v;
  } else if (t < NX + NW1) {
    int u = t - NX;
    int lane = u & 63, mt = (u >> 6) & 15, n = u >> 10;
    int m = lane & 15, q = lane >> 4;
    int outc = mt * 16 + m;
    unsigned short v[8];
#pragma unroll
    for (int j = 0; j < 8; j++) {
      int k = q * 8 + j;
      v[j] = (k < 23) ? f2bf(W1[(n * 23 + k) * 256 + outc]) : (unsigned short)0;
    }
    *(uint4*)&w1p[(size_t)u * 8] = *(const uint4*)v;
  } else {
    // 32x32x16 A-frag order: lane holds A[ch = mt*32 + l31][k = kt*16 + lh*8 + j]
    int u = t - NX - NW1;                   // < 81920 = NQ*16*8*64
    int lane = u & 63, mt = (u >> 6) & 7, kt = (u >> 9) & 15, n = u >> 13;
    int l31 = lane & 31, lh = lane >> 5;
    int ch = mt * 32 + l31;                 // output channel (h_out)
    unsigned short v[8];
#pragma unroll
    for (int j = 0; j < 8; j++) {
      int k = kt * 16 + lh * 8 + j;         // input channel (h_in)
      v[j] = f2bf(W2[((size_t)(n * 256 + k)) * 256 + ch]);
    }
    *(uint4*)&w2p[(size_t)u * 8] = *(const uint4*)v;
  }
}

// ---- fused MLP: 5120 blocks x 512 threads (8 waves), 3 blocks/CU ----
// wave w: cg = w>>1 (64 channels), colg = w&1 (32 batch cols)
__global__ __launch_bounds__(512, 6) void fused_ensemble_kernel(
    const unsigned short* __restrict__ xp,
    const unsigned short* __restrict__ w1p,
    const float* __restrict__ b1,
    const unsigned short* __restrict__ w2p,
    const float* __restrict__ b2,
    const float* __restrict__ W3,
    const float* __restrict__ b3,
    float* __restrict__ out) {
  __shared__ __align__(16) unsigned short hs[32 * BT * 8];  // 32 KB, [ch/8][col][8]
  __shared__ float red[8 * 32];                             // 1 KB cross-wave reduce

  const int tid = threadIdx.x;
  const int lane = tid & 63;
  const int w = tid >> 6;
  const int m = lane & 15;      // 16x16 indices (layer 1)
  const int q = lane >> 4;
  const int l31 = lane & 31;    // 32x32 indices (layer 2)
  const int lh = lane >> 5;
  const int cg = w >> 1;        // channels [cg*64, cg*64+64)
  const int colg = w & 1;       // cols [colg*32, colg*32+32)

  const int n = blockIdx.x >> 9;            // 512 tiles per net
  const int row0 = (blockIdx.x & 511) * BT;

  const unsigned short* w2n = w2p + (size_t)n * (16 * 8 * 64 * 8);

  // ---- layer 1: 16x16x32, single K-step; wave tile 64ch x 32col (4x2 frags) ----
  f32x4 acc[4][2];
  {
    bf16x8 af[4], bfr[2];
#pragma unroll
    for (int nt = 0; nt < 2; nt++) {
      int col = row0 + colg * 32 + nt * 16 + m;
      bfr[nt] = *(const bf16x8*)(xp + (size_t)col * 32 + q * 8);
    }
#pragma unroll
    for (int mt = 0; mt < 4; mt++)
      af[mt] = *(const bf16x8*)(w1p + (((size_t)n * 16 + cg * 4 + mt) * 64 + lane) * 8);
#pragma unroll
    for (int mt = 0; mt < 4; mt++) {
      float4 bv = *(const float4*)&b1[n * HDIM + (cg * 4 + mt) * 16 + q * 4];
      f32x4 bi = (f32x4){bv.x, bv.y, bv.z, bv.w};
#pragma unroll
      for (int nt = 0; nt < 2; nt++) acc[mt][nt] = bi;
    }
#pragma unroll
    for (int nt = 0; nt < 2; nt++)
#pragma unroll
      for (int mt = 0; mt < 4; mt++)
        acc[mt][nt] = __builtin_amdgcn_mfma_f32_16x16x32_bf16(af[mt], bfr[nt], acc[mt][nt], 0, 0, 0);
  }

  // ---- prefetch layer-2 kt=0 A-frags + bias init (independent of h1) ----
  bf16x8 acur[2], anxt[2], bcur, bnxt;
#pragma unroll
  for (int mt = 0; mt < 2; mt++)
    acur[mt] = *(const bf16x8*)(w2n + (((size_t)cg * 2 + mt) * 64 + lane) * 8);

  f32x16 acc2[2];
#pragma unroll
  for (int mt = 0; mt < 2; mt++) {
    // D reg r: ch = cg*64 + mt*32 + (r&3) + 8*(r>>2) + 4*lh
    int chb = n * HDIM + cg * 64 + mt * 32 + 4 * lh;
    float4 bv0 = *(const float4*)&b2[chb + 0];
    float4 bv1 = *(const float4*)&b2[chb + 8];
    float4 bv2 = *(const float4*)&b2[chb + 16];
    float4 bv3 = *(const float4*)&b2[chb + 24];
    f32x16 bi;
    bi[0] = bv0.x; bi[1] = bv0.y; bi[2] = bv0.z; bi[3] = bv0.w;
    bi[4] = bv1.x; bi[5] = bv1.y; bi[6] = bv1.z; bi[7] = bv1.w;
    bi[8] = bv2.x; bi[9] = bv2.y; bi[10] = bv2.z; bi[11] = bv2.w;
    bi[12] = bv3.x; bi[13] = bv3.y; bi[14] = bv3.z; bi[15] = bv3.w;
    acc2[mt] = bi;
  }

  // ---- epilogue 1: relu -> h1 bf16, frag-chunk layout [ch/8][col][8] ----
#pragma unroll
  for (int mt = 0; mt < 4; mt++) {
    int kq = cg * 8 + mt * 2 + (q >> 1);
    int joff = (q & 1) * 4;
#pragma unroll
    for (int nt = 0; nt < 2; nt++) {
      int col = colg * 32 + nt * 16 + m;
      f32x4 a = acc[mt][nt];
      uint2 wv;
      wv.x = pk2bf(fmaxf(a[0], 0.f), fmaxf(a[1], 0.f));
      wv.y = pk2bf(fmaxf(a[2], 0.f), fmaxf(a[3], 0.f));
      *(uint2*)&hs[((size_t)kq * BT + col) * 8 + joff] = wv;
    }
  }
  __syncthreads();

  // ---- layer 2: 32x32x16, 16 K-steps, A (L2) + B (LDS) depth-1 prefetch ----
  {
    bcur = *(const bf16x8*)&hs[(((size_t)lh) * BT + colg * 32 + l31) * 8];
#pragma unroll
    for (int kt = 0; kt < 16; kt++) {
      if (kt < 15) {
#pragma unroll
        for (int mt = 0; mt < 2; mt++)
          anxt[mt] = *(const bf16x8*)(w2n + (((size_t)(kt + 1) * 8 + cg * 2 + mt) * 64 + lane) * 8);
        bnxt = *(const bf16x8*)&hs[(((size_t)(kt + 1) * 2 + lh) * BT + colg * 32 + l31) * 8];
      }
#pragma unroll
      for (int mt = 0; mt < 2; mt++)
        acc2[mt] = __builtin_amdgcn_mfma_f32_32x32x16_bf16(acur[mt], bcur, acc2[mt], 0, 0, 0);
      if (kt < 15) {
#pragma unroll
        for (int mt = 0; mt < 2; mt++) acur[mt] = anxt[mt];
        bcur = bnxt;
      }
    }
  }

  // ---- layer 3 in-register: p[col] = sum_ch relu(acc2_ch) * W3[ch] ----
  {
    float4 w3v[2][4];
#pragma unroll
    for (int mt = 0; mt < 2; mt++) {
      int chb = n * HDIM + cg * 64 + mt * 32 + 4 * lh;
      w3v[mt][0] = *(const float4*)&W3[chb + 0];
      w3v[mt][1] = *(const float4*)&W3[chb + 8];
      w3v[mt][2] = *(const float4*)&W3[chb + 16];
      w3v[mt][3] = *(const float4*)&W3[chb + 24];
    }
    float s = 0.f;
#pragma unroll
    for (int mt = 0; mt < 2; mt++)
#pragma unroll
      for (int g = 0; g < 4; g++) {
        const float4 wv = w3v[mt][g];
        s = fmaf(fmaxf(acc2[mt][g * 4 + 0], 0.f), wv.x, s);
        s = fmaf(fmaxf(acc2[mt][g * 4 + 1], 0.f), wv.y, s);
        s = fmaf(fmaxf(acc2[mt][g * 4 + 2], 0.f), wv.z, s);
        s = fmaf(fmaxf(acc2[mt][g * 4 + 3], 0.f), wv.w, s);
      }
    s += __shfl_xor(s, 32, 64);   // combine lh halves (disjoint channel sets)
    if (lh == 0) red[w * 32 + l31] = s;
    __syncthreads();
    if (tid < BT) {
      int g = tid >> 5, lc = tid & 31;       // col group, local col
      float sum = b3[n];
#pragma unroll
      for (int c = 0; c < 4; c++) sum += red[(c * 2 + g) * 32 + lc];
      out[(size_t)n * B_TOTAL + row0 + tid] = sum;
    }
  }
}

extern "C" void kernel_launch(void* const* d_in, const int* in_sizes, int n_in,
                              void* d_out, int out_size, void* d_ws, size_t ws_size,
                              hipStream_t stream) {
  const float* state  = (const float*)d_in[0];
  const float* action = (const float*)d_in[1];
  const float* W1 = (const float*)d_in[2];
  const float* b1 = (const float*)d_in[3];
  const float* W2 = (const float*)d_in[4];
  const float* b2 = (const float*)d_in[5];
  const float* W3 = (const float*)d_in[6];
  const float* b3 = (const float*)d_in[7];
  float* out = (float*)d_out;

  unsigned short* xp  = (unsigned short*)d_ws;                                    // 2,097,152 B
  unsigned short* w1p = (unsigned short*)((char*)d_ws + (size_t)XP_ELEMS * 2);    //   163,840 B
  unsigned short* w2p = (unsigned short*)((char*)d_ws + (size_t)(XP_ELEMS + W1P_ELEMS) * 2); // 1,310,720 B

  pack_all_kernel<<<872, 256, 0, stream>>>(state, action, W1, W2, xp, w1p, w2p);
  fused_ensemble_kernel<<<NQ * (B_TOTAL / BT), 512, 0, stream>>>(
      xp, w1p, b1, w2p, b2, W3, b3, out);
}

// Round 7
// 120.648 us; speedup vs baseline: 1.1661x; 1.1661x over previous
//
#include <hip/hip_runtime.h>
#include <hip/hip_bf16.h>

// Ensemble Q-network, fused, transposed ([features x batch]).
//   h1^T = relu(W1^T x^T + b1);  acc = W2^T h1^T + b2;  out = W3 . relu(acc)  in-register.
// R7 = R4 structure (BT=128, 16x16x32 MFMA both layers, 2560 blocks x 512 thr,
// 2 blocks/CU) + software-pipelined K-loop: even/odd slot rotation, slot kt&1
// reloaded with kt+2's A (L2) and B (LDS) frags right after its MFMAs consume it
// -> ~2 K-steps (~155+ cyc) of latency cover with the SAME 64 queue VGPRs as R4
// (combined VGPR+AGPR stays at the 128 / 4-waves-per-SIMD budget).

typedef __attribute__((ext_vector_type(8))) short bf16x8;   // 8 bf16 (4 VGPRs)
typedef __attribute__((ext_vector_type(4))) float f32x4;    // MFMA C/D

#define B_TOTAL 32768
#define NQ 10
#define HDIM 256
#define BT 128

#define XP_ELEMS  (B_TOTAL * 32)            // bf16 x, k-padded to 32
#define W1P_ELEMS (NQ * 16 * 64 * 8)        // [n][mtile16][lane64][j8]
#define W2P_ELEMS (NQ * 8 * 16 * 64 * 8)    // [n][kt8][mtile16][lane64][j8]

__device__ __forceinline__ unsigned short f2bf(float f) {
  unsigned int u = __float_as_uint(f);
  u = u + 0x7FFFu + ((u >> 16) & 1u);
  return (unsigned short)(u >> 16);
}

__device__ __forceinline__ unsigned int pk2bf(float a, float b) {
  union { __hip_bfloat162 h; unsigned int u; } cv;
  cv.h = __float22bfloat162_rn(make_float2(a, b));
  return cv.u;
}

// ---- single pack dispatch: x, W1^T (16x16 A-order), W2^T (16x16 A-order) ----
__global__ void pack_all_kernel(const float* __restrict__ state,
                                const float* __restrict__ action,
                                const float* __restrict__ W1,
                                const float* __restrict__ W2,
                                unsigned short* __restrict__ xp,
                                unsigned short* __restrict__ w1p,
                                unsigned short* __restrict__ w2p) {
  int t = blockIdx.x * 256 + threadIdx.x;   // 872 * 256 = 223232 exactly
  const int NX  = B_TOTAL * 4;              // 131072 uint4 chunks of xp
  const int NW1 = NQ * 16 * 64;             // 10240
  if (t < NX) {
    int b = t >> 2, seg = t & 3;
    unsigned short v[8];
    if (seg < 2) {
      const float* sp = state + (size_t)b * 17 + seg * 8;
#pragma unroll
      for (int j = 0; j < 8; j++) v[j] = f2bf(sp[j]);
    } else if (seg == 2) {
      v[0] = f2bf(state[(size_t)b * 17 + 16]);
#pragma unroll
      for (int j = 0; j < 6; j++) v[1 + j] = f2bf(action[(size_t)b * 6 + j]);
      v[7] = 0;
    } else {
#pragma unroll
      for (int j = 0; j < 8; j++) v[j] = 0;
    }
    *(uint4*)&xp[(size_t)t * 8] = *(const uint4*)v;
  } else if (t < NX + NW1) {
    int u = t - NX;
    int lane = u & 63, mt = (u >> 6) & 15, n = u >> 10;
    int m = lane & 15, q = lane >> 4;
    int outc = mt * 16 + m;
    unsigned short v[8];
#pragma unroll
    for (int j = 0; j < 8; j++) {
      int k = q * 8 + j;
      v[j] = (k < 23) ? f2bf(W1[(n * 23 + k) * 256 + outc]) : (unsigned short)0;
    }
    *(uint4*)&w1p[(size_t)u * 8] = *(const uint4*)v;
  } else {
    int u = t - NX - NW1;                   // < 81920
    int lane = u & 63, mt = (u >> 6) & 15, kt = (u >> 10) & 7, n = u >> 13;
    int m = lane & 15, q = lane >> 4;
    int outc = mt * 16 + m;
    unsigned short v[8];
#pragma unroll
    for (int j = 0; j < 8; j++) {
      int h = kt * 32 + q * 8 + j;
      v[j] = f2bf(W2[((size_t)(n * 256 + h)) * 256 + outc]);
    }
    *(uint4*)&w2p[(size_t)u * 8] = *(const uint4*)v;
  }
}

// ---- fused MLP: 2560 blocks x 512 threads (8 waves), 2 blocks/CU ----
// wave w: cg = w>>1 (64 channels), colg = w&1 (64 batch cols)
__global__ __launch_bounds__(512, 4) void fused_ensemble_kernel(
    const unsigned short* __restrict__ xp,
    const unsigned short* __restrict__ w1p,
    const float* __restrict__ b1,
    const unsigned short* __restrict__ w2p,
    const float* __restrict__ b2,
    const float* __restrict__ W3,
    const float* __restrict__ b3,
    float* __restrict__ out) {
  __shared__ __align__(16) unsigned short hs[32 * BT * 8];  // 64 KB, [ch/8][col][8]
  __shared__ float red[8 * 64];                             // 2 KB cross-wave reduce

  const int tid = threadIdx.x;
  const int lane = tid & 63;
  const int w = tid >> 6;
  const int m = lane & 15;
  const int q = lane >> 4;
  const int cg = w >> 1;        // channels [cg*64, cg*64+64)
  const int colg = w & 1;       // cols [colg*64, colg*64+64)

  const int n = blockIdx.x >> 8;            // 256 tiles per net
  const int row0 = (blockIdx.x & 255) * BT;

  const unsigned short* w2n = w2p + (size_t)n * (8 * 16 * 64 * 8);

  // ---- layer 1: 16x16x32, single K-step; wave tile 64ch x 64col (4x4 frags) ----
  f32x4 acc[4][4];
  {
    bf16x8 af[4], bfr[4];
#pragma unroll
    for (int nt = 0; nt < 4; nt++) {
      int col = row0 + colg * 64 + nt * 16 + m;
      bfr[nt] = *(const bf16x8*)(xp + (size_t)col * 32 + q * 8);
    }
#pragma unroll
    for (int mt = 0; mt < 4; mt++)
      af[mt] = *(const bf16x8*)(w1p + (((size_t)n * 16 + cg * 4 + mt) * 64 + lane) * 8);
#pragma unroll
    for (int mt = 0; mt < 4; mt++) {
      float4 bv = *(const float4*)&b1[n * HDIM + (cg * 4 + mt) * 16 + q * 4];
      f32x4 bi = (f32x4){bv.x, bv.y, bv.z, bv.w};
#pragma unroll
      for (int nt = 0; nt < 4; nt++) acc[mt][nt] = bi;
    }
#pragma unroll
    for (int nt = 0; nt < 4; nt++)
#pragma unroll
      for (int mt = 0; mt < 4; mt++)
        acc[mt][nt] = __builtin_amdgcn_mfma_f32_16x16x32_bf16(af[mt], bfr[nt], acc[mt][nt], 0, 0, 0);
  }

  // ---- pipeline preload: layer-2 A-frag slots for kt=0,1 (global; no h1 dep) ----
  bf16x8 aS[2][4];   // even/odd K-step slots
  bf16x8 bS[2][4];
#pragma unroll
  for (int sl = 0; sl < 2; sl++)
#pragma unroll
    for (int mt = 0; mt < 4; mt++)
      aS[sl][mt] = *(const bf16x8*)(w2n + (((size_t)sl * 16 + cg * 4 + mt) * 64 + lane) * 8);

  f32x4 acc2[4][4];
#pragma unroll
  for (int mt = 0; mt < 4; mt++) {
    float4 bv = *(const float4*)&b2[n * HDIM + (cg * 4 + mt) * 16 + q * 4];
    f32x4 bi = (f32x4){bv.x, bv.y, bv.z, bv.w};
#pragma unroll
    for (int nt = 0; nt < 4; nt++) acc2[mt][nt] = bi;
  }

  // ---- epilogue 1: relu -> h1 bf16, frag-chunk layout [ch/8][col][8] ----
#pragma unroll
  for (int mt = 0; mt < 4; mt++) {
    int kq = cg * 8 + mt * 2 + (q >> 1);
    int joff = (q & 1) * 4;
#pragma unroll
    for (int nt = 0; nt < 4; nt++) {
      int col = colg * 64 + nt * 16 + m;
      f32x4 a = acc[mt][nt];
      uint2 wv;
      wv.x = pk2bf(fmaxf(a[0], 0.f), fmaxf(a[1], 0.f));
      wv.y = pk2bf(fmaxf(a[2], 0.f), fmaxf(a[3], 0.f));
      *(uint2*)&hs[((size_t)kq * BT + col) * 8 + joff] = wv;
    }
  }
  __syncthreads();

  // ---- layer 2: 8 K-steps, even/odd slot rotation (reload slot with kt+2
  //      right after its MFMAs consume it -> ~2-step latency cover, no extra regs)
  {
#pragma unroll
    for (int sl = 0; sl < 2; sl++)
#pragma unroll
      for (int nt = 0; nt < 4; nt++)
        bS[sl][nt] = *(const bf16x8*)&hs[(((size_t)sl * 4 + q) * BT + colg * 64 + nt * 16 + m) * 8];

#pragma unroll
    for (int kt = 0; kt < 8; kt++) {
      const int sl = kt & 1;
#pragma unroll
      for (int nt = 0; nt < 4; nt++)
#pragma unroll
        for (int mt = 0; mt < 4; mt++)
          acc2[mt][nt] = __builtin_amdgcn_mfma_f32_16x16x32_bf16(
              aS[sl][mt], bS[sl][nt], acc2[mt][nt], 0, 0, 0);
      if (kt + 2 < 8) {
#pragma unroll
        for (int mt = 0; mt < 4; mt++)
          aS[sl][mt] = *(const bf16x8*)(w2n + (((size_t)(kt + 2) * 16 + cg * 4 + mt) * 64 + lane) * 8);
#pragma unroll
        for (int nt = 0; nt < 4; nt++)
          bS[sl][nt] = *(const bf16x8*)&hs[(((size_t)(kt + 2) * 4 + q) * BT + colg * 64 + nt * 16 + m) * 8];
      }
    }
  }

  // ---- layer 3 in-register: p[col] = sum_ch relu(acc2_ch) * W3[ch]; reduce ----
  {
    float4 w3v[4];
#pragma unroll
    for (int mt = 0; mt < 4; mt++)
      w3v[mt] = *(const float4*)&W3[n * HDIM + (cg * 4 + mt) * 16 + q * 4];
    float p[4];
#pragma unroll
    for (int nt = 0; nt < 4; nt++) {
      float s = 0.f;
#pragma unroll
      for (int mt = 0; mt < 4; mt++) {
        f32x4 a = acc2[mt][nt];
        float4 wv = w3v[mt];
        s = fmaf(fmaxf(a[0], 0.f), wv.x, s);
        s = fmaf(fmaxf(a[1], 0.f), wv.y, s);
        s = fmaf(fmaxf(a[2], 0.f), wv.z, s);
        s = fmaf(fmaxf(a[3], 0.f), wv.w, s);
      }
      s += __shfl_xor(s, 16, 64);   // reduce q within wave (channels)
      s += __shfl_xor(s, 32, 64);
      p[nt] = s;
    }
    if (q == 0) {
#pragma unroll
      for (int nt = 0; nt < 4; nt++) red[w * 64 + nt * 16 + m] = p[nt];
    }
    __syncthreads();
    if (tid < BT) {
      int g = tid >> 6, lc = tid & 63;       // col group, local col
      float s = b3[n];
#pragma unroll
      for (int c = 0; c < 4; c++) s += red[(c * 2 + g) * 64 + lc];
      out[(size_t)n * B_TOTAL + row0 + tid] = s;
    }
  }
}

extern "C" void kernel_launch(void* const* d_in, const int* in_sizes, int n_in,
                              void* d_out, int out_size, void* d_ws, size_t ws_size,
                              hipStream_t stream) {
  const float* state  = (const float*)d_in[0];
  const float* action = (const float*)d_in[1];
  const float* W1 = (const float*)d_in[2];
  const float* b1 = (const float*)d_in[3];
  const float* W2 = (const float*)d_in[4];
  const float* b2 = (const float*)d_in[5];
  const float* W3 = (const float*)d_in[6];
  const float* b3 = (const float*)d_in[7];
  float* out = (float*)d_out;

  unsigned short* xp  = (unsigned short*)d_ws;                                    // 2,097,152 B
  unsigned short* w1p = (unsigned short*)((char*)d_ws + (size_t)XP_ELEMS * 2);    //   163,840 B
  unsigned short* w2p = (unsigned short*)((char*)d_ws + (size_t)(XP_ELEMS + W1P_ELEMS) * 2); // 1,310,720 B

  pack_all_kernel<<<872, 256, 0, stream>>>(state, action, W1, W2, xp, w1p, w2p);
  fused_ensemble_kernel<<<NQ * (B_TOTAL / BT), 512, 0, stream>>>(
      xp, w1p, b1, w2p, b2, W3, b3, out);
}